// Round 12
// baseline (875.358 us; speedup 1.0000x reference)
//
#include <hip/hip_runtime.h>
#include <hip/hip_bf16.h>
#include <hip/hip_fp16.h>
#include <cmath>

// CrAKN fused implementation.
// R12 = R10 bias chain verbatim (R11's barrier/epilogue changes regressed and
// were reverted) + softmax fused away: logits_kernel stores exp(logit)
// (bounded |logit|<~40 -> no max-subtraction needed in fp32) and atomically
// accumulates per-row sums; attnv scales by 1/sum. Saves 4 dispatches and
// 8 MB/layer of logits round-trip.

namespace {

constexpr int kN   = 512;
constexpr int kD   = 64;
constexpr int kH   = 4;
constexpr int kHD  = 128;
constexpr int kHHD = 512;
constexpr int kFB  = 256;
constexpr int kK   = 100;
constexpr float kEps   = 1e-5f;
constexpr float kScale = 0.08838834764831845f; // 1/sqrt(128)

typedef unsigned short u16;
typedef unsigned int u32;
typedef short bf16x8 __attribute__((ext_vector_type(8)));   // raw 16B container
typedef _Float16 f16x8 __attribute__((ext_vector_type(8)));
typedef float f32x4 __attribute__((ext_vector_type(4)));

// mish(x) = x - 2x*rcp(e*(e+2)+2), e = exp(x). Exact identity; no clamp:
// e=inf -> rcp(inf)=0 -> mish=x (true asymptote); e=0 -> 0.
__device__ __forceinline__ float mish_f(float x) {
    float e  = __expf(x);
    float n2 = fmaf(e, e + 2.0f, 2.0f);
    return fmaf(x + x, -__builtin_amdgcn_rcpf(n2), x);
}

__device__ __forceinline__ u32 pkh(float a, float b) {
    union { __half2 h; u32 u; } cv;
    cv.h = __float22half2_rn(make_float2(a, b));
    return cv.u; // a low 16, b high 16
}
__device__ __forceinline__ f16x8 mkh8(u32 a, u32 b, u32 c, u32 d) {
    union { u32 w[4]; f16x8 v; } cv;
    cv.w[0] = a; cv.w[1] = b; cv.w[2] = c; cv.w[3] = d;
    return cv.v;
}
__device__ __forceinline__ u16 f16_bits(float f) {
    union { __half h; u16 u; } cv;
    cv.h = __float2half(f);
    return cv.u;
}

__device__ __forceinline__ void ld4(float* d, const float* s) {
    float4 v = *(const float4*)s;
    d[0] = v.x; d[1] = v.y; d[2] = v.z; d[3] = v.w;
}

// ---------------- embed + LN1, and b0 = amds @ bias_emb ----------------
__global__ __launch_bounds__(64) void embed_kernel(
    const float* __restrict__ nf, const float* __restrict__ amds,
    const float* __restrict__ emb_W, const float* __restrict__ emb_b,
    const float* __restrict__ bemb_W, const float* __restrict__ bemb_b,
    const float* __restrict__ ln1_g, const float* __restrict__ ln1_b,
    float* __restrict__ x, float* __restrict__ b0)
{
    const int n = blockIdx.x;
    const int d = threadIdx.x;
    __shared__ float s_row[kFB];
    #pragma unroll
    for (int r = 0; r < kFB / kD; ++r) s_row[r * kD + d] = nf[n * kFB + r * kD + d];
    __syncthreads();
    float acc = emb_b[d];
    for (int k = 0; k < kFB; ++k) acc = fmaf(s_row[k], emb_W[k * kD + d], acc);
    float mu = acc;
    #pragma unroll
    for (int off = 32; off > 0; off >>= 1) mu += __shfl_xor(mu, off);
    mu *= (1.0f / kD);
    float dv = acc - mu;
    float var = dv * dv;
    #pragma unroll
    for (int off = 32; off > 0; off >>= 1) var += __shfl_xor(var, off);
    var *= (1.0f / kD);
    x[n * kD + d] = dv * rsqrtf(var + kEps) * ln1_g[d] + ln1_b[d];
    __syncthreads();
    s_row[d] = amds[n * kK + d];
    if (d < kK - kD) s_row[kD + d] = amds[n * kK + kD + d];
    __syncthreads();
    float bacc = bemb_b[d];
    for (int k = 0; k < kK; ++k) bacc = fmaf(s_row[k], bemb_W[k * kD + d], bacc);
    b0[n * kD + d] = bacc;
}

// ---------------- bias[i,j,d] = fp16(b0[j,d] - b0[i,d]) ----------------
__global__ __launch_bounds__(256) void bias_init_kernel(
    const float* __restrict__ b0, u16* __restrict__ bias)
{
    int gid = blockIdx.x * 256 + threadIdx.x;
    int d8 = gid & 7;
    int j  = (gid >> 3) & (kN - 1);
    int i  = gid >> 12;
    const float4* bj = (const float4*)(b0 + j * kD + d8 * 8);
    const float4* bi = (const float4*)(b0 + i * kD + d8 * 8);
    float4 a0 = bj[0], a1 = bj[1];
    float4 c0 = bi[0], c1 = bi[1];
    union { u32 w[4]; bf16x8 v; } cv;
    cv.w[0] = pkh(a0.x - c0.x, a0.y - c0.y);
    cv.w[1] = pkh(a0.z - c0.z, a0.w - c0.w);
    cv.w[2] = pkh(a1.x - c1.x, a1.y - c1.y);
    cv.w[3] = pkh(a1.z - c1.z, a1.w - c1.w);
    *(bf16x8*)(bias + (long)gid * 8) = cv.v;
}

// ---------------- per-launch weight prep: transpose + fp16 ----------------
__global__ __launch_bounds__(256) void prep_weights_kernel(
    const float* __restrict__ diff_W, const float* __restrict__ bout_W,
    u16* __restrict__ dWt, u16* __restrict__ boutWt)
{
    int gid = blockIdx.x * 256 + threadIdx.x; // 2 * 4 * 32768
    if (gid < 4 * 32768) {
        int e = gid;
        int l = e >> 15;
        int r = e & 32767;
        int k = r >> 9;
        int n = r & 511;
        dWt[l * 32768 + n * 64 + k] = f16_bits(diff_W[e]);
    } else {
        int e = gid - 4 * 32768;
        int l = e >> 15;
        int r = e & 32767;
        int k = r >> 6;
        int d = r & 63;
        boutWt[l * 32768 + d * 512 + k] = f16_bits(bout_W[e]);
    }
}

// ---------------- zero per-row softmax sums ----------------
__global__ __launch_bounds__(256) void zero_sums_kernel(float* __restrict__ sums)
{
    sums[blockIdx.x * 256 + threadIdx.x] = 0.0f;
}

// ---------------- qkv = x @ qkv_W[l] + qkv_b[l] ----------------
__global__ __launch_bounds__(256) void qkv_kernel(
    const float* __restrict__ x, const float* __restrict__ W,
    const float* __restrict__ b, float* __restrict__ qkv)
{
    const int n = blockIdx.y;
    const int c = blockIdx.x * 256 + threadIdx.x;
    __shared__ float s_x[kD];
    if (threadIdx.x < kD) s_x[threadIdx.x] = x[n * kD + threadIdx.x];
    __syncthreads();
    float acc = b[c];
    #pragma unroll 8
    for (int d = 0; d < kD; ++d) acc = fmaf(s_x[d], W[d * (3 * kHHD) + c], acc);
    qkv[n * (3 * kHHD) + c] = acc;
}

// ---------------- fused pair-bias chain, fp16 MFMA (R10 version) ----------
// Block = 128 pairs (4 waves x 32). Per 32-becol group-pair g2:
//   GEMM1 (be^T): A = W1^T rows permuted so that the C output at lane (q,c),
//   tile u, reg r holds be[pair=c][bc = 32*g2 + 8q + 4u + r] == the A-frag
//   element k=quad*8+j (j=4u+r) for GEMM2 (16x16x32; layout dtype-indep).
//   GEMM2: acc2 += be_chunk @ W2 chunk (skipped when last: bias dead).
// bias is fp16 in global (B-frags load raw). LDS stages W1/W2 fp16 chunks
// (XOR-swizzled, double-buffered), 1 barrier/g2.
__global__ __launch_bounds__(256, 4) void bias_layer_mfma(
    u16* __restrict__ bias,
    const u16* __restrict__ dWt, const u16* __restrict__ boutWt,
    const float* __restrict__ diff_b, const float* __restrict__ bout_b,
    float* __restrict__ diffs, int last)
{
    // [buf][ w1: 32 rows * 64 u16 | w2 at 2048: 64 rows * 32 u16 ]
    __shared__ u16 s_w[2][4096]; // 16 KB

    const int t    = threadIdx.x;
    const int w    = t >> 6;
    const int lane = t & 63;
    const int q    = lane >> 4;    // quad
    const int c    = lane & 15;
    const int pb   = blockIdx.x * 128 + w * 32;  // wave's 32 pairs

    // --- staging indices (per thread): W1 row-permuted + k-block XOR swizzle
    const int sb_bc  = t >> 3;       // source W1^T row within chunk (0..31)
    const int sb_kb  = t & 7;        // k block (8 u16 each)
    const int sr     = ((sb_bc >> 2) & 1) * 16 + ((sb_bc >> 3) << 2) + (sb_bc & 3);
    const int w1_dst = sr * 64 + (sb_kb ^ (sr & 7)) * 8;
    const int sb_d   = t >> 2;       // W2 row d (0..63)
    const int sb_k2  = t & 3;        // k block within 32
    const int w2_dst = 2048 + sb_d * 32 + (sb_k2 ^ ((sb_d >> 1) & 3)) * 8;
    const u16* g_w1 = dWt + sb_bc * 64 + sb_kb * 8;
    const u16* g_w2 = boutWt + sb_d * 512 + sb_k2 * 8;

    // --- B-frags: bias^T (fp16, raw load) for two 16-pair tiles, K=64
    f16x8 Bf[2][2];
    #pragma unroll
    for (int mt = 0; mt < 2; ++mt) {
        #pragma unroll
        for (int s = 0; s < 2; ++s) {
            Bf[mt][s] = *(const f16x8*)(bias + (long)(pb + mt * 16 + c) * kD + s * 32 + q * 8);
        }
    }

    // --- prologue stage g2=0 into buf 0
    {
        bf16x8 r0 = *(const bf16x8*)g_w1;
        bf16x8 r1 = *(const bf16x8*)g_w2;
        *(bf16x8*)&s_w[0][w1_dst] = r0;
        *(bf16x8*)&s_w[0][w2_dst] = r1;
    }
    __syncthreads();

    f32x4 acc2[2][4];
    #pragma unroll
    for (int mt = 0; mt < 2; ++mt)
        #pragma unroll
        for (int dg = 0; dg < 4; ++dg) acc2[mt][dg] = (f32x4)0.0f;
    float psum[2][4];
    #pragma unroll
    for (int mt = 0; mt < 2; ++mt)
        #pragma unroll
        for (int h = 0; h < 4; ++h) psum[mt][h] = 0.0f;

    const int sw1 = c & 7;          // W1 read swizzle key
    const int sw2 = (c >> 1) & 3;   // W2 read swizzle key
    int cur = 0;

    for (int g2 = 0; g2 < 16; ++g2) {
        // prefetch next weight chunk into regs (committed after compute)
        bf16x8 r0, r1;
        if (g2 < 15) {
            r0 = *(const bf16x8*)(g_w1 + (g2 + 1) * 2048);
            r1 = *(const bf16x8*)(g_w2 + (g2 + 1) * 32);
        }

        // ---- GEMM1: a1[mt][u] = W1^T(permuted rows) x bias^T  (fp16)
        f32x4 a1[2][2];
        #pragma unroll
        for (int mt = 0; mt < 2; ++mt)
            #pragma unroll
            for (int u = 0; u < 2; ++u) a1[mt][u] = (f32x4)0.0f;
        const u16* w1 = &s_w[cur][0];
        #pragma unroll
        for (int u = 0; u < 2; ++u) {
            int row = (u * 16 + c) * 64;
            int o0 = row + ((0 + q) ^ sw1) * 8; // s=0 (k 0..31)
            int o1 = row + ((4 + q) ^ sw1) * 8; // s=1 (k 32..63)
            f16x8 A0 = *(const f16x8*)(w1 + o0);
            f16x8 A1 = *(const f16x8*)(w1 + o1);
            #pragma unroll
            for (int mt = 0; mt < 2; ++mt) {
                a1[mt][u] = __builtin_amdgcn_mfma_f32_16x16x32_f16(A0, Bf[mt][0], a1[mt][u], 0, 0, 0);
                a1[mt][u] = __builtin_amdgcn_mfma_f32_16x16x32_f16(A1, Bf[mt][1], a1[mt][u], 0, 0, 0);
            }
        }

        // ---- mish + psum + fp16 pack; C-layout IS GEMM2 A-layout (j = 4u+r)
        const int hd = g2 >> 2;
        f16x8 A2[2];
        #pragma unroll
        for (int mt = 0; mt < 2; ++mt) {
            u32 p[2][2];
            #pragma unroll
            for (int u = 0; u < 2; ++u) {
                float4 db = *(const float4*)(diff_b + g2 * 32 + q * 8 + u * 4);
                float v0 = mish_f(a1[mt][u][0] + db.x);
                float v1 = mish_f(a1[mt][u][1] + db.y);
                float v2 = mish_f(a1[mt][u][2] + db.z);
                float v3 = mish_f(a1[mt][u][3] + db.w);
                psum[mt][hd] += v0 * v0 + v1 * v1 + v2 * v2 + v3 * v3;
                p[u][0] = pkh(v0, v1);
                p[u][1] = pkh(v2, v3);
            }
            A2[mt] = mkh8(p[0][0], p[0][1], p[1][0], p[1][1]);
        }

        // ---- GEMM2: acc2 += be_chunk @ W2 chunk (fp16); dead in last layer
        if (!last) {
            const u16* w2 = &s_w[cur][2048];
            const int kb2 = (q ^ sw2) * 8;
            #pragma unroll
            for (int dg = 0; dg < 4; ++dg) {
                int bo = dg * 512 + c * 32 + kb2;
                f16x8 Wf = *(const f16x8*)(w2 + bo);
                #pragma unroll
                for (int mt = 0; mt < 2; ++mt) {
                    acc2[mt][dg] = __builtin_amdgcn_mfma_f32_16x16x32_f16(A2[mt], Wf, acc2[mt][dg], 0, 0, 0);
                }
            }
        }

        // ---- commit prefetched chunk, flip buffers
        if (g2 < 15) {
            int nb = cur ^ 1;
            *(bf16x8*)&s_w[nb][w1_dst] = r0;
            *(bf16x8*)&s_w[nb][w2_dst] = r1;
            __syncthreads();
            cur = nb;
        }
    }

    // ---- epilogue: bias tile in place (fp16) + diffs
    if (!last) {
        #pragma unroll
        for (int mt = 0; mt < 2; ++mt) {
            #pragma unroll
            for (int dg = 0; dg < 4; ++dg) {
                float bb = bout_b[dg * 16 + c];
                #pragma unroll
                for (int r = 0; r < 4; ++r) {
                    float v = mish_f(acc2[mt][dg][r] + bb);
                    bias[(long)(pb + mt * 16 + 4 * q + r) * kD + dg * 16 + c] = f16_bits(v);
                }
            }
        }
    }
    const int i  = blockIdx.x >> 2;
    const int jb = (blockIdx.x & 3) * 128 + w * 32;
    #pragma unroll
    for (int mt = 0; mt < 2; ++mt) {
        #pragma unroll
        for (int h = 0; h < 4; ++h) {
            psum[mt][h] += __shfl_xor(psum[mt][h], 16);
            psum[mt][h] += __shfl_xor(psum[mt][h], 32);
        }
        float sv = (q == 0) ? psum[mt][0] : (q == 1) ? psum[mt][1]
                 : (q == 2) ? psum[mt][2] : psum[mt][3];
        diffs[q * (kN * kN) + i * kN + jb + mt * 16 + c] = sqrtf(sv);
    }
}

// ---- attn_unnorm[h,n,m] = exp(scale*q.k + diffs); sums[h,n] += row partials
__global__ __launch_bounds__(256) void logits_kernel(
    const float* __restrict__ qkv, const float* __restrict__ diffs,
    float* __restrict__ attn, float* __restrict__ sums)
{
    constexpr int SW = 68;
    __shared__ float s_q[64 * SW];
    __shared__ float s_k[64 * SW];
    const int t  = threadIdx.x;
    const int tX = t & 15;
    const int tY = t >> 4;
    const int h  = blockIdx.z;
    const int n0 = blockIdx.x * 64;
    const int m0 = blockIdx.y * 64;

    float acc[4][4];
    #pragma unroll
    for (int a = 0; a < 4; ++a)
        #pragma unroll
        for (int b = 0; b < 4; ++b) acc[a][b] = 0.0f;

    for (int dc = 0; dc < 2; ++dc) {
        __syncthreads();
        #pragma unroll
        for (int rep = 0; rep < 4; ++rep) {
            int f = rep * 256 + t;
            int row = f >> 4;
            int c4  = f & 15;
            *(float4*)&s_q[row * SW + c4 * 4] =
                *(const float4*)&qkv[(n0 + row) * (3 * kHHD) + h * 384 + dc * 64 + c4 * 4];
            *(float4*)&s_k[row * SW + c4 * 4] =
                *(const float4*)&qkv[(m0 + row) * (3 * kHHD) + h * 384 + 128 + dc * 64 + c4 * 4];
        }
        __syncthreads();
        for (int d = 0; d < 64; d += 4) {
            float a[4][4], b[4][4];
            #pragma unroll
            for (int rr = 0; rr < 4; ++rr) ld4(a[rr], &s_q[(tY + 16 * rr) * SW + d]);
            #pragma unroll
            for (int cc = 0; cc < 4; ++cc) ld4(b[cc], &s_k[(tX + 16 * cc) * SW + d]);
            #pragma unroll
            for (int rr = 0; rr < 4; ++rr)
                #pragma unroll
                for (int cc = 0; cc < 4; ++cc)
                    #pragma unroll
                    for (int u = 0; u < 4; ++u)
                        acc[rr][cc] = fmaf(a[rr][u], b[cc][u], acc[rr][cc]);
        }
    }
    #pragma unroll
    for (int rr = 0; rr < 4; ++rr) {
        int row = n0 + tY + 16 * rr;
        float rsum = 0.0f;
        #pragma unroll
        for (int cc = 0; cc < 4; ++cc) {
            int col = m0 + tX + 16 * cc;
            long idx = (long)h * (kN * kN) + (long)row * kN + col;
            // |logit| < ~40 here, so exp without max-subtraction is fp32-safe
            float p = __expf(acc[rr][cc] * kScale + diffs[idx]);
            attn[idx] = p;
            rsum += p;
        }
        // reduce across the 16 tX lanes (same tY): lanes differ in bits 0..3
        rsum += __shfl_xor(rsum, 1);
        rsum += __shfl_xor(rsum, 2);
        rsum += __shfl_xor(rsum, 4);
        rsum += __shfl_xor(rsum, 8);
        if (tX == 0) atomicAdd(&sums[h * kN + row], rsum);
    }
}

// ---- vals[n, h*128+d] = (sum_m attn_unnorm[h,n,m]*v[m,h,d]) / sums[h,n] ----
__global__ __launch_bounds__(256) void attnv_kernel(
    const float* __restrict__ attn, const float* __restrict__ qkv,
    const float* __restrict__ sums, float* __restrict__ vals)
{
    constexpr int SW = 68;
    __shared__ float s_p[32 * SW];
    __shared__ float s_v[64 * SW];
    const int t  = threadIdx.x;
    const int tx = t & 15;
    const int ty = t >> 4;
    const int h  = blockIdx.z;
    const int n0 = blockIdx.x * 32;
    const int d0 = blockIdx.y * 64;

    float acc[2][4];
    #pragma unroll
    for (int a = 0; a < 2; ++a)
        #pragma unroll
        for (int b = 0; b < 4; ++b) acc[a][b] = 0.0f;

    for (int mt = 0; mt < 8; ++mt) {
        const int m0 = mt * 64;
        __syncthreads();
        #pragma unroll
        for (int rep = 0; rep < 2; ++rep) {
            int f = rep * 256 + t;
            int row = f >> 4;
            int c4  = f & 15;
            *(float4*)&s_p[row * SW + c4 * 4] =
                *(const float4*)&attn[(long)h * (kN * kN) + (long)(n0 + row) * kN + m0 + c4 * 4];
        }
        #pragma unroll
        for (int rep = 0; rep < 4; ++rep) {
            int f = rep * 256 + t;
            int row = f >> 4;
            int c4  = f & 15;
            *(float4*)&s_v[row * SW + c4 * 4] =
                *(const float4*)&qkv[(m0 + row) * (3 * kHHD) + h * 384 + 256 + d0 + c4 * 4];
        }
        __syncthreads();
        for (int kk = 0; kk < 64; kk += 4) {
            float a[2][4], b[4][4];
            #pragma unroll
            for (int rr = 0; rr < 2; ++rr) ld4(a[rr], &s_p[(ty + 16 * rr) * SW + kk]);
            #pragma unroll
            for (int u = 0; u < 4; ++u) ld4(b[u], &s_v[(kk + u) * SW + 4 * tx]);
            #pragma unroll
            for (int rr = 0; rr < 2; ++rr)
                #pragma unroll
                for (int cc = 0; cc < 4; ++cc)
                    #pragma unroll
                    for (int u = 0; u < 4; ++u)
                        acc[rr][cc] = fmaf(a[rr][u], b[u][cc], acc[rr][cc]);
        }
    }
    #pragma unroll
    for (int rr = 0; rr < 2; ++rr) {
        float inv = 1.0f / sums[h * kN + n0 + ty + 16 * rr];
        float4 o = make_float4(acc[rr][0] * inv, acc[rr][1] * inv,
                               acc[rr][2] * inv, acc[rr][3] * inv);
        *(float4*)&vals[(long)(n0 + ty + 16 * rr) * kHHD + h * kHD + d0 + 4 * tx] = o;
    }
}

// ---------------- x = LN2(x + vals@o_W + o_b) ----------------
__global__ __launch_bounds__(64) void oproj_ln_kernel(
    const float* __restrict__ vals, const float* __restrict__ o_W,
    const float* __restrict__ o_b, const float* __restrict__ g2,
    const float* __restrict__ b2, float* __restrict__ x)
{
    const int n = blockIdx.x;
    const int d = threadIdx.x;
    __shared__ float s_v[kHHD];
    #pragma unroll
    for (int r = 0; r < kHHD / kD; ++r) s_v[r * kD + d] = vals[n * kHHD + r * kD + d];
    __syncthreads();
    float acc = o_b[d];
    for (int j = 0; j < kHHD; ++j) acc = fmaf(s_v[j], o_W[j * kD + d], acc);
    float xv = x[n * kD + d] + acc;
    float mu = xv;
    #pragma unroll
    for (int off = 32; off > 0; off >>= 1) mu += __shfl_xor(mu, off);
    mu *= (1.0f / kD);
    float dv = xv - mu;
    float var = dv * dv;
    #pragma unroll
    for (int off = 32; off > 0; off >>= 1) var += __shfl_xor(var, off);
    var *= (1.0f / kD);
    x[n * kD + d] = dv * rsqrtf(var + kEps) * g2[d] + b2[d];
}

// ---------------- out = x @ out_W + out_b ----------------
__global__ __launch_bounds__(64) void final_kernel(
    const float* __restrict__ x, const float* __restrict__ out_W,
    const float* __restrict__ out_b, float* __restrict__ out)
{
    const int n = blockIdx.x * 64 + threadIdx.x;
    float acc = out_b[0];
    #pragma unroll
    for (int d = 0; d < kD; ++d) acc = fmaf(x[n * kD + d], out_W[d], acc);
    out[n] = acc;
}

} // anonymous namespace

extern "C" void kernel_launch(void* const* d_in, const int* in_sizes, int n_in,
                              void* d_out, int out_size, void* d_ws, size_t ws_size,
                              hipStream_t stream)
{
    (void)in_sizes; (void)n_in; (void)out_size; (void)ws_size;

    const float* nf     = (const float*)d_in[0];
    const float* amds   = (const float*)d_in[1];
    const float* emb_W  = (const float*)d_in[2];
    const float* emb_b  = (const float*)d_in[3];
    const float* bemb_W = (const float*)d_in[4];
    const float* bemb_b = (const float*)d_in[5];
    const float* ln1_g  = (const float*)d_in[6];
    const float* ln1_b  = (const float*)d_in[7];
    const float* ln2_g  = (const float*)d_in[8];
    const float* ln2_b  = (const float*)d_in[9];
    const float* qkv_W  = (const float*)d_in[10];
    const float* qkv_b  = (const float*)d_in[11];
    const float* diff_W = (const float*)d_in[12];
    const float* diff_b = (const float*)d_in[13];
    const float* o_W    = (const float*)d_in[14];
    const float* o_b    = (const float*)d_in[15];
    const float* bout_W = (const float*)d_in[16];
    const float* bout_b = (const float*)d_in[17];
    const float* out_W  = (const float*)d_in[18];
    const float* out_b  = (const float*)d_in[19];

    float* ws = (float*)d_ws;
    float* ws_x      = ws;                   // 512*64
    float* ws_b0     = ws_x + 32768;         // 512*64
    float* ws_qkv    = ws_b0 + 32768;        // 512*1536
    float* ws_vals   = ws_qkv + 786432;      // 512*512
    float* ws_diffs  = ws_vals + 262144;     // 4*512*512
    float* ws_attn   = ws_diffs + 1048576;   // 4*512*512 (unnormalized exp)
    u16*   ws_bias   = (u16*)(ws_attn + 1048576); // 512*512*64 fp16 (33.5 MB)
    u16*   dWt       = ws_bias + 16777216;   // 4*512*64  fp16
    u16*   boutWt    = dWt + 131072;         // 4*64*512  fp16
    float* ws_sums   = (float*)(boutWt + 131072); // 4*512 row sums

    embed_kernel<<<kN, kD, 0, stream>>>(nf, amds, emb_W, emb_b, bemb_W, bemb_b,
                                        ln1_g, ln1_b, ws_x, ws_b0);
    bias_init_kernel<<<(kN * kN * kD / 8) / 256, 256, 0, stream>>>(ws_b0, ws_bias);
    prep_weights_kernel<<<(2 * 4 * 32768) / 256, 256, 0, stream>>>(
        diff_W, bout_W, dWt, boutWt);

    for (int l = 0; l < 4; ++l) {
        qkv_kernel<<<dim3(6, kN), 256, 0, stream>>>(
            ws_x, qkv_W + l * kD * (3 * kHHD), qkv_b + l * (3 * kHHD), ws_qkv);
        bias_layer_mfma<<<kN * kN / 128, 256, 0, stream>>>(
            ws_bias, dWt + l * 32768, boutWt + l * 32768,
            diff_b + l * kHHD, bout_b + l * kD, ws_diffs, (l == 3) ? 1 : 0);
        zero_sums_kernel<<<(kH * kN) / 256, 256, 0, stream>>>(ws_sums);
        logits_kernel<<<dim3(8, 8, kH), 256, 0, stream>>>(
            ws_qkv, ws_diffs, ws_attn, ws_sums);
        attnv_kernel<<<dim3(16, 2, kH), 256, 0, stream>>>(
            ws_attn, ws_qkv, ws_sums, ws_vals);
        oproj_ln_kernel<<<kN, kD, 0, stream>>>(
            ws_vals, o_W + l * kHHD * kD, o_b + l * kD, ln2_g, ln2_b, ws_x);
    }
    final_kernel<<<kN / kD, kD, 0, stream>>>(ws_x, out_W, out_b, (float*)d_out);
}

// Round 13
// 659.852 us; speedup vs baseline: 1.3266x; 1.3266x over previous
//
#include <hip/hip_runtime.h>
#include <hip/hip_bf16.h>
#include <hip/hip_fp16.h>
#include <cmath>

// CrAKN fused implementation.
// R13 = R10 bias chain (+ no-clamp mish, verified -5us) + softmax fused with
// ZERO cross-block communication: logits stores exp(logit) (bounded, fp32-
// safe); attnv accumulates each row's sum from the P-tiles it already reads
// (a[rr] is kk-indexed only -> every thread sees the full row) and divides at
// the end. R12's atomic/zero_sums machinery (VGPR-256 blowup) removed.

namespace {

constexpr int kN   = 512;
constexpr int kD   = 64;
constexpr int kH   = 4;
constexpr int kHD  = 128;
constexpr int kHHD = 512;
constexpr int kFB  = 256;
constexpr int kK   = 100;
constexpr float kEps   = 1e-5f;
constexpr float kScale = 0.08838834764831845f; // 1/sqrt(128)

typedef unsigned short u16;
typedef unsigned int u32;
typedef short bf16x8 __attribute__((ext_vector_type(8)));   // raw 16B container
typedef _Float16 f16x8 __attribute__((ext_vector_type(8)));
typedef float f32x4 __attribute__((ext_vector_type(4)));

// mish(x) = x - 2x*rcp(e*(e+2)+2), e = exp(x). Exact identity; no clamp:
// e=inf -> rcp(inf)=0 -> mish=x (true asymptote); e=0 -> 0.
__device__ __forceinline__ float mish_f(float x) {
    float e  = __expf(x);
    float n2 = fmaf(e, e + 2.0f, 2.0f);
    return fmaf(x + x, -__builtin_amdgcn_rcpf(n2), x);
}

__device__ __forceinline__ u32 pkh(float a, float b) {
    union { __half2 h; u32 u; } cv;
    cv.h = __float22half2_rn(make_float2(a, b));
    return cv.u; // a low 16, b high 16
}
__device__ __forceinline__ f16x8 mkh8(u32 a, u32 b, u32 c, u32 d) {
    union { u32 w[4]; f16x8 v; } cv;
    cv.w[0] = a; cv.w[1] = b; cv.w[2] = c; cv.w[3] = d;
    return cv.v;
}
__device__ __forceinline__ u16 f16_bits(float f) {
    union { __half h; u16 u; } cv;
    cv.h = __float2half(f);
    return cv.u;
}

__device__ __forceinline__ void ld4(float* d, const float* s) {
    float4 v = *(const float4*)s;
    d[0] = v.x; d[1] = v.y; d[2] = v.z; d[3] = v.w;
}

// ---------------- embed + LN1, and b0 = amds @ bias_emb ----------------
__global__ __launch_bounds__(64) void embed_kernel(
    const float* __restrict__ nf, const float* __restrict__ amds,
    const float* __restrict__ emb_W, const float* __restrict__ emb_b,
    const float* __restrict__ bemb_W, const float* __restrict__ bemb_b,
    const float* __restrict__ ln1_g, const float* __restrict__ ln1_b,
    float* __restrict__ x, float* __restrict__ b0)
{
    const int n = blockIdx.x;
    const int d = threadIdx.x;
    __shared__ float s_row[kFB];
    #pragma unroll
    for (int r = 0; r < kFB / kD; ++r) s_row[r * kD + d] = nf[n * kFB + r * kD + d];
    __syncthreads();
    float acc = emb_b[d];
    for (int k = 0; k < kFB; ++k) acc = fmaf(s_row[k], emb_W[k * kD + d], acc);
    float mu = acc;
    #pragma unroll
    for (int off = 32; off > 0; off >>= 1) mu += __shfl_xor(mu, off);
    mu *= (1.0f / kD);
    float dv = acc - mu;
    float var = dv * dv;
    #pragma unroll
    for (int off = 32; off > 0; off >>= 1) var += __shfl_xor(var, off);
    var *= (1.0f / kD);
    x[n * kD + d] = dv * rsqrtf(var + kEps) * ln1_g[d] + ln1_b[d];
    __syncthreads();
    s_row[d] = amds[n * kK + d];
    if (d < kK - kD) s_row[kD + d] = amds[n * kK + kD + d];
    __syncthreads();
    float bacc = bemb_b[d];
    for (int k = 0; k < kK; ++k) bacc = fmaf(s_row[k], bemb_W[k * kD + d], bacc);
    b0[n * kD + d] = bacc;
}

// ---------------- bias[i,j,d] = fp16(b0[j,d] - b0[i,d]) ----------------
__global__ __launch_bounds__(256) void bias_init_kernel(
    const float* __restrict__ b0, u16* __restrict__ bias)
{
    int gid = blockIdx.x * 256 + threadIdx.x;
    int d8 = gid & 7;
    int j  = (gid >> 3) & (kN - 1);
    int i  = gid >> 12;
    const float4* bj = (const float4*)(b0 + j * kD + d8 * 8);
    const float4* bi = (const float4*)(b0 + i * kD + d8 * 8);
    float4 a0 = bj[0], a1 = bj[1];
    float4 c0 = bi[0], c1 = bi[1];
    union { u32 w[4]; bf16x8 v; } cv;
    cv.w[0] = pkh(a0.x - c0.x, a0.y - c0.y);
    cv.w[1] = pkh(a0.z - c0.z, a0.w - c0.w);
    cv.w[2] = pkh(a1.x - c1.x, a1.y - c1.y);
    cv.w[3] = pkh(a1.z - c1.z, a1.w - c1.w);
    *(bf16x8*)(bias + (long)gid * 8) = cv.v;
}

// ---------------- per-launch weight prep: transpose + fp16 ----------------
__global__ __launch_bounds__(256) void prep_weights_kernel(
    const float* __restrict__ diff_W, const float* __restrict__ bout_W,
    u16* __restrict__ dWt, u16* __restrict__ boutWt)
{
    int gid = blockIdx.x * 256 + threadIdx.x; // 2 * 4 * 32768
    if (gid < 4 * 32768) {
        int e = gid;
        int l = e >> 15;
        int r = e & 32767;
        int k = r >> 9;
        int n = r & 511;
        dWt[l * 32768 + n * 64 + k] = f16_bits(diff_W[e]);
    } else {
        int e = gid - 4 * 32768;
        int l = e >> 15;
        int r = e & 32767;
        int k = r >> 6;
        int d = r & 63;
        boutWt[l * 32768 + d * 512 + k] = f16_bits(bout_W[e]);
    }
}

// ---------------- qkv = x @ qkv_W[l] + qkv_b[l] ----------------
__global__ __launch_bounds__(256) void qkv_kernel(
    const float* __restrict__ x, const float* __restrict__ W,
    const float* __restrict__ b, float* __restrict__ qkv)
{
    const int n = blockIdx.y;
    const int c = blockIdx.x * 256 + threadIdx.x;
    __shared__ float s_x[kD];
    if (threadIdx.x < kD) s_x[threadIdx.x] = x[n * kD + threadIdx.x];
    __syncthreads();
    float acc = b[c];
    #pragma unroll 8
    for (int d = 0; d < kD; ++d) acc = fmaf(s_x[d], W[d * (3 * kHHD) + c], acc);
    qkv[n * (3 * kHHD) + c] = acc;
}

// ---------------- fused pair-bias chain, fp16 MFMA (R10 version) ----------
// Block = 128 pairs (4 waves x 32). Per 32-becol group-pair g2:
//   GEMM1 (be^T): A = W1^T rows permuted so that the C output at lane (q,c),
//   tile u, reg r holds be[pair=c][bc = 32*g2 + 8q + 4u + r] == the A-frag
//   element k=quad*8+j (j=4u+r) for GEMM2 (16x16x32; layout dtype-indep).
//   GEMM2: acc2 += be_chunk @ W2 chunk (skipped when last: bias dead).
// bias is fp16 in global (B-frags load raw). LDS stages W1/W2 fp16 chunks
// (XOR-swizzled, double-buffered), 1 barrier/g2.
__global__ __launch_bounds__(256, 4) void bias_layer_mfma(
    u16* __restrict__ bias,
    const u16* __restrict__ dWt, const u16* __restrict__ boutWt,
    const float* __restrict__ diff_b, const float* __restrict__ bout_b,
    float* __restrict__ diffs, int last)
{
    // [buf][ w1: 32 rows * 64 u16 | w2 at 2048: 64 rows * 32 u16 ]
    __shared__ u16 s_w[2][4096]; // 16 KB

    const int t    = threadIdx.x;
    const int w    = t >> 6;
    const int lane = t & 63;
    const int q    = lane >> 4;    // quad
    const int c    = lane & 15;
    const int pb   = blockIdx.x * 128 + w * 32;  // wave's 32 pairs

    // --- staging indices (per thread): W1 row-permuted + k-block XOR swizzle
    const int sb_bc  = t >> 3;       // source W1^T row within chunk (0..31)
    const int sb_kb  = t & 7;        // k block (8 u16 each)
    const int sr     = ((sb_bc >> 2) & 1) * 16 + ((sb_bc >> 3) << 2) + (sb_bc & 3);
    const int w1_dst = sr * 64 + (sb_kb ^ (sr & 7)) * 8;
    const int sb_d   = t >> 2;       // W2 row d (0..63)
    const int sb_k2  = t & 3;        // k block within 32
    const int w2_dst = 2048 + sb_d * 32 + (sb_k2 ^ ((sb_d >> 1) & 3)) * 8;
    const u16* g_w1 = dWt + sb_bc * 64 + sb_kb * 8;
    const u16* g_w2 = boutWt + sb_d * 512 + sb_k2 * 8;

    // --- B-frags: bias^T (fp16, raw load) for two 16-pair tiles, K=64
    f16x8 Bf[2][2];
    #pragma unroll
    for (int mt = 0; mt < 2; ++mt) {
        #pragma unroll
        for (int s = 0; s < 2; ++s) {
            Bf[mt][s] = *(const f16x8*)(bias + (long)(pb + mt * 16 + c) * kD + s * 32 + q * 8);
        }
    }

    // --- prologue stage g2=0 into buf 0
    {
        bf16x8 r0 = *(const bf16x8*)g_w1;
        bf16x8 r1 = *(const bf16x8*)g_w2;
        *(bf16x8*)&s_w[0][w1_dst] = r0;
        *(bf16x8*)&s_w[0][w2_dst] = r1;
    }
    __syncthreads();

    f32x4 acc2[2][4];
    #pragma unroll
    for (int mt = 0; mt < 2; ++mt)
        #pragma unroll
        for (int dg = 0; dg < 4; ++dg) acc2[mt][dg] = (f32x4)0.0f;
    float psum[2][4];
    #pragma unroll
    for (int mt = 0; mt < 2; ++mt)
        #pragma unroll
        for (int h = 0; h < 4; ++h) psum[mt][h] = 0.0f;

    const int sw1 = c & 7;          // W1 read swizzle key
    const int sw2 = (c >> 1) & 3;   // W2 read swizzle key
    int cur = 0;

    for (int g2 = 0; g2 < 16; ++g2) {
        // prefetch next weight chunk into regs (committed after compute)
        bf16x8 r0, r1;
        if (g2 < 15) {
            r0 = *(const bf16x8*)(g_w1 + (g2 + 1) * 2048);
            r1 = *(const bf16x8*)(g_w2 + (g2 + 1) * 32);
        }

        // ---- GEMM1: a1[mt][u] = W1^T(permuted rows) x bias^T  (fp16)
        f32x4 a1[2][2];
        #pragma unroll
        for (int mt = 0; mt < 2; ++mt)
            #pragma unroll
            for (int u = 0; u < 2; ++u) a1[mt][u] = (f32x4)0.0f;
        const u16* w1 = &s_w[cur][0];
        #pragma unroll
        for (int u = 0; u < 2; ++u) {
            int row = (u * 16 + c) * 64;
            int o0 = row + ((0 + q) ^ sw1) * 8; // s=0 (k 0..31)
            int o1 = row + ((4 + q) ^ sw1) * 8; // s=1 (k 32..63)
            f16x8 A0 = *(const f16x8*)(w1 + o0);
            f16x8 A1 = *(const f16x8*)(w1 + o1);
            #pragma unroll
            for (int mt = 0; mt < 2; ++mt) {
                a1[mt][u] = __builtin_amdgcn_mfma_f32_16x16x32_f16(A0, Bf[mt][0], a1[mt][u], 0, 0, 0);
                a1[mt][u] = __builtin_amdgcn_mfma_f32_16x16x32_f16(A1, Bf[mt][1], a1[mt][u], 0, 0, 0);
            }
        }

        // ---- mish + psum + fp16 pack; C-layout IS GEMM2 A-layout (j = 4u+r)
        const int hd = g2 >> 2;
        f16x8 A2[2];
        #pragma unroll
        for (int mt = 0; mt < 2; ++mt) {
            u32 p[2][2];
            #pragma unroll
            for (int u = 0; u < 2; ++u) {
                float4 db = *(const float4*)(diff_b + g2 * 32 + q * 8 + u * 4);
                float v0 = mish_f(a1[mt][u][0] + db.x);
                float v1 = mish_f(a1[mt][u][1] + db.y);
                float v2 = mish_f(a1[mt][u][2] + db.z);
                float v3 = mish_f(a1[mt][u][3] + db.w);
                psum[mt][hd] += v0 * v0 + v1 * v1 + v2 * v2 + v3 * v3;
                p[u][0] = pkh(v0, v1);
                p[u][1] = pkh(v2, v3);
            }
            A2[mt] = mkh8(p[0][0], p[0][1], p[1][0], p[1][1]);
        }

        // ---- GEMM2: acc2 += be_chunk @ W2 chunk (fp16); dead in last layer
        if (!last) {
            const u16* w2 = &s_w[cur][2048];
            const int kb2 = (q ^ sw2) * 8;
            #pragma unroll
            for (int dg = 0; dg < 4; ++dg) {
                int bo = dg * 512 + c * 32 + kb2;
                f16x8 Wf = *(const f16x8*)(w2 + bo);
                #pragma unroll
                for (int mt = 0; mt < 2; ++mt) {
                    acc2[mt][dg] = __builtin_amdgcn_mfma_f32_16x16x32_f16(A2[mt], Wf, acc2[mt][dg], 0, 0, 0);
                }
            }
        }

        // ---- commit prefetched chunk, flip buffers
        if (g2 < 15) {
            int nb = cur ^ 1;
            *(bf16x8*)&s_w[nb][w1_dst] = r0;
            *(bf16x8*)&s_w[nb][w2_dst] = r1;
            __syncthreads();
            cur = nb;
        }
    }

    // ---- epilogue: bias tile in place (fp16) + diffs
    if (!last) {
        #pragma unroll
        for (int mt = 0; mt < 2; ++mt) {
            #pragma unroll
            for (int dg = 0; dg < 4; ++dg) {
                float bb = bout_b[dg * 16 + c];
                #pragma unroll
                for (int r = 0; r < 4; ++r) {
                    float v = mish_f(acc2[mt][dg][r] + bb);
                    bias[(long)(pb + mt * 16 + 4 * q + r) * kD + dg * 16 + c] = f16_bits(v);
                }
            }
        }
    }
    const int i  = blockIdx.x >> 2;
    const int jb = (blockIdx.x & 3) * 128 + w * 32;
    #pragma unroll
    for (int mt = 0; mt < 2; ++mt) {
        #pragma unroll
        for (int h = 0; h < 4; ++h) {
            psum[mt][h] += __shfl_xor(psum[mt][h], 16);
            psum[mt][h] += __shfl_xor(psum[mt][h], 32);
        }
        float sv = (q == 0) ? psum[mt][0] : (q == 1) ? psum[mt][1]
                 : (q == 2) ? psum[mt][2] : psum[mt][3];
        diffs[q * (kN * kN) + i * kN + jb + mt * 16 + c] = sqrtf(sv);
    }
}

// ---- attn_unnorm[h,n,m] = exp(scale*q.k + diffs) (no reduction here) ----
__global__ __launch_bounds__(256) void logits_kernel(
    const float* __restrict__ qkv, const float* __restrict__ diffs,
    float* __restrict__ attn)
{
    constexpr int SW = 68;
    __shared__ float s_q[64 * SW];
    __shared__ float s_k[64 * SW];
    const int t  = threadIdx.x;
    const int tX = t & 15;
    const int tY = t >> 4;
    const int h  = blockIdx.z;
    const int n0 = blockIdx.x * 64;
    const int m0 = blockIdx.y * 64;

    float acc[4][4];
    #pragma unroll
    for (int a = 0; a < 4; ++a)
        #pragma unroll
        for (int b = 0; b < 4; ++b) acc[a][b] = 0.0f;

    for (int dc = 0; dc < 2; ++dc) {
        __syncthreads();
        #pragma unroll
        for (int rep = 0; rep < 4; ++rep) {
            int f = rep * 256 + t;
            int row = f >> 4;
            int c4  = f & 15;
            *(float4*)&s_q[row * SW + c4 * 4] =
                *(const float4*)&qkv[(n0 + row) * (3 * kHHD) + h * 384 + dc * 64 + c4 * 4];
            *(float4*)&s_k[row * SW + c4 * 4] =
                *(const float4*)&qkv[(m0 + row) * (3 * kHHD) + h * 384 + 128 + dc * 64 + c4 * 4];
        }
        __syncthreads();
        for (int d = 0; d < 64; d += 4) {
            float a[4][4], b[4][4];
            #pragma unroll
            for (int rr = 0; rr < 4; ++rr) ld4(a[rr], &s_q[(tY + 16 * rr) * SW + d]);
            #pragma unroll
            for (int cc = 0; cc < 4; ++cc) ld4(b[cc], &s_k[(tX + 16 * cc) * SW + d]);
            #pragma unroll
            for (int rr = 0; rr < 4; ++rr)
                #pragma unroll
                for (int cc = 0; cc < 4; ++cc)
                    #pragma unroll
                    for (int u = 0; u < 4; ++u)
                        acc[rr][cc] = fmaf(a[rr][u], b[cc][u], acc[rr][cc]);
        }
    }
    #pragma unroll
    for (int rr = 0; rr < 4; ++rr)
        #pragma unroll
        for (int cc = 0; cc < 4; ++cc) {
            int row = n0 + tY + 16 * rr;
            int col = m0 + tX + 16 * cc;
            long idx = (long)h * (kN * kN) + (long)row * kN + col;
            // |logit| < ~40 here -> exp without max-subtraction is fp32-safe
            attn[idx] = __expf(acc[rr][cc] * kScale + diffs[idx]);
        }
}

// ---- vals[n,h*128+d] = (sum_m P[h,n,m]*v[m,h,d]) / (sum_m P[h,n,m]) --------
// Row sums computed in-block: a[rr] is kk-indexed only, so each thread reads
// its rows' FULL P vector across the mt/kk loops -> accumulate rsum locally.
__global__ __launch_bounds__(256) void attnv_kernel(
    const float* __restrict__ attn, const float* __restrict__ qkv,
    float* __restrict__ vals)
{
    constexpr int SW = 68;
    __shared__ float s_p[32 * SW];
    __shared__ float s_v[64 * SW];
    const int t  = threadIdx.x;
    const int tx = t & 15;
    const int ty = t >> 4;
    const int h  = blockIdx.z;
    const int n0 = blockIdx.x * 32;
    const int d0 = blockIdx.y * 64;

    float acc[2][4];
    float rsum[2];
    #pragma unroll
    for (int a = 0; a < 2; ++a) {
        rsum[a] = 0.0f;
        #pragma unroll
        for (int b = 0; b < 4; ++b) acc[a][b] = 0.0f;
    }

    for (int mt = 0; mt < 8; ++mt) {
        const int m0 = mt * 64;
        __syncthreads();
        #pragma unroll
        for (int rep = 0; rep < 2; ++rep) {
            int f = rep * 256 + t;
            int row = f >> 4;
            int c4  = f & 15;
            *(float4*)&s_p[row * SW + c4 * 4] =
                *(const float4*)&attn[(long)h * (kN * kN) + (long)(n0 + row) * kN + m0 + c4 * 4];
        }
        #pragma unroll
        for (int rep = 0; rep < 4; ++rep) {
            int f = rep * 256 + t;
            int row = f >> 4;
            int c4  = f & 15;
            *(float4*)&s_v[row * SW + c4 * 4] =
                *(const float4*)&qkv[(m0 + row) * (3 * kHHD) + h * 384 + 256 + d0 + c4 * 4];
        }
        __syncthreads();
        for (int kk = 0; kk < 64; kk += 4) {
            float a[2][4], b[4][4];
            #pragma unroll
            for (int rr = 0; rr < 2; ++rr) ld4(a[rr], &s_p[(ty + 16 * rr) * SW + kk]);
            #pragma unroll
            for (int u = 0; u < 4; ++u) ld4(b[u], &s_v[(kk + u) * SW + 4 * tx]);
            #pragma unroll
            for (int rr = 0; rr < 2; ++rr) {
                rsum[rr] += (a[rr][0] + a[rr][1]) + (a[rr][2] + a[rr][3]);
                #pragma unroll
                for (int cc = 0; cc < 4; ++cc)
                    #pragma unroll
                    for (int u = 0; u < 4; ++u)
                        acc[rr][cc] = fmaf(a[rr][u], b[u][cc], acc[rr][cc]);
            }
        }
    }
    #pragma unroll
    for (int rr = 0; rr < 2; ++rr) {
        float inv = 1.0f / rsum[rr];
        float4 o = make_float4(acc[rr][0] * inv, acc[rr][1] * inv,
                               acc[rr][2] * inv, acc[rr][3] * inv);
        *(float4*)&vals[(long)(n0 + ty + 16 * rr) * kHHD + h * kHD + d0 + 4 * tx] = o;
    }
}

// ---------------- x = LN2(x + vals@o_W + o_b) ----------------
__global__ __launch_bounds__(64) void oproj_ln_kernel(
    const float* __restrict__ vals, const float* __restrict__ o_W,
    const float* __restrict__ o_b, const float* __restrict__ g2,
    const float* __restrict__ b2, float* __restrict__ x)
{
    const int n = blockIdx.x;
    const int d = threadIdx.x;
    __shared__ float s_v[kHHD];
    #pragma unroll
    for (int r = 0; r < kHHD / kD; ++r) s_v[r * kD + d] = vals[n * kHHD + r * kD + d];
    __syncthreads();
    float acc = o_b[d];
    for (int j = 0; j < kHHD; ++j) acc = fmaf(s_v[j], o_W[j * kD + d], acc);
    float xv = x[n * kD + d] + acc;
    float mu = xv;
    #pragma unroll
    for (int off = 32; off > 0; off >>= 1) mu += __shfl_xor(mu, off);
    mu *= (1.0f / kD);
    float dv = xv - mu;
    float var = dv * dv;
    #pragma unroll
    for (int off = 32; off > 0; off >>= 1) var += __shfl_xor(var, off);
    var *= (1.0f / kD);
    x[n * kD + d] = dv * rsqrtf(var + kEps) * g2[d] + b2[d];
}

// ---------------- out = x @ out_W + out_b ----------------
__global__ __launch_bounds__(64) void final_kernel(
    const float* __restrict__ x, const float* __restrict__ out_W,
    const float* __restrict__ out_b, float* __restrict__ out)
{
    const int n = blockIdx.x * 64 + threadIdx.x;
    float acc = out_b[0];
    #pragma unroll
    for (int d = 0; d < kD; ++d) acc = fmaf(x[n * kD + d], out_W[d], acc);
    out[n] = acc;
}

} // anonymous namespace

extern "C" void kernel_launch(void* const* d_in, const int* in_sizes, int n_in,
                              void* d_out, int out_size, void* d_ws, size_t ws_size,
                              hipStream_t stream)
{
    (void)in_sizes; (void)n_in; (void)out_size; (void)ws_size;

    const float* nf     = (const float*)d_in[0];
    const float* amds   = (const float*)d_in[1];
    const float* emb_W  = (const float*)d_in[2];
    const float* emb_b  = (const float*)d_in[3];
    const float* bemb_W = (const float*)d_in[4];
    const float* bemb_b = (const float*)d_in[5];
    const float* ln1_g  = (const float*)d_in[6];
    const float* ln1_b  = (const float*)d_in[7];
    const float* ln2_g  = (const float*)d_in[8];
    const float* ln2_b  = (const float*)d_in[9];
    const float* qkv_W  = (const float*)d_in[10];
    const float* qkv_b  = (const float*)d_in[11];
    const float* diff_W = (const float*)d_in[12];
    const float* diff_b = (const float*)d_in[13];
    const float* o_W    = (const float*)d_in[14];
    const float* o_b    = (const float*)d_in[15];
    const float* bout_W = (const float*)d_in[16];
    const float* bout_b = (const float*)d_in[17];
    const float* out_W  = (const float*)d_in[18];
    const float* out_b  = (const float*)d_in[19];

    float* ws = (float*)d_ws;
    float* ws_x      = ws;                   // 512*64
    float* ws_b0     = ws_x + 32768;         // 512*64
    float* ws_qkv    = ws_b0 + 32768;        // 512*1536
    float* ws_vals   = ws_qkv + 786432;      // 512*512
    float* ws_diffs  = ws_vals + 262144;     // 4*512*512
    float* ws_attn   = ws_diffs + 1048576;   // 4*512*512 (unnormalized exp)
    u16*   ws_bias   = (u16*)(ws_attn + 1048576); // 512*512*64 fp16 (33.5 MB)
    u16*   dWt       = ws_bias + 16777216;   // 4*512*64  fp16
    u16*   boutWt    = dWt + 131072;         // 4*64*512  fp16

    embed_kernel<<<kN, kD, 0, stream>>>(nf, amds, emb_W, emb_b, bemb_W, bemb_b,
                                        ln1_g, ln1_b, ws_x, ws_b0);
    bias_init_kernel<<<(kN * kN * kD / 8) / 256, 256, 0, stream>>>(ws_b0, ws_bias);
    prep_weights_kernel<<<(2 * 4 * 32768) / 256, 256, 0, stream>>>(
        diff_W, bout_W, dWt, boutWt);

    for (int l = 0; l < 4; ++l) {
        qkv_kernel<<<dim3(6, kN), 256, 0, stream>>>(
            ws_x, qkv_W + l * kD * (3 * kHHD), qkv_b + l * (3 * kHHD), ws_qkv);
        bias_layer_mfma<<<kN * kN / 128, 256, 0, stream>>>(
            ws_bias, dWt + l * 32768, boutWt + l * 32768,
            diff_b + l * kHHD, bout_b + l * kD, ws_diffs, (l == 3) ? 1 : 0);
        logits_kernel<<<dim3(8, 8, kH), 256, 0, stream>>>(ws_qkv, ws_diffs, ws_attn);
        attnv_kernel<<<dim3(16, 2, kH), 256, 0, stream>>>(ws_attn, ws_qkv, ws_vals);
        oproj_ln_kernel<<<kN, kD, 0, stream>>>(
            ws_vals, o_W + l * kHHD * kD, o_b + l * kD, ln2_g, ln2_b, ws_x);
    }
    final_kernel<<<kN / kD, kD, 0, stream>>>(ws_x, out_W, out_b, (float*)d_out);
}